// Round 6
// baseline (135.127 us; speedup 1.0000x reference)
//
#include <hip/hip_runtime.h>

#define C_TOT 64
#define Dd 48
#define Hh 128
#define Ww 128
#define HW (Hh*Ww)
#define DHW (Dd*HW)
#define CSPLIT 8
#define SROW 37             // stage row stride (floats), odd => bank spread
#define NPL 14              // max staged z-planes (rd<=12 -> span<=13.25)
#define PRE 5               // prefetch regs/thread (covers 5120 elems)
#define CAP (PRE*1024)

typedef float lf2 __attribute__((ext_vector_type(2), aligned(4)));

__device__ __forceinline__ void axis_interp(float c, int dim, int& lo, int& hi,
                                            float& fr, bool& valid) {
    valid = (c >= -1.0f) && (c <= (float)dim);
    c = fminf(fmaxf(c, 0.0f), (float)(dim - 1));
    float l = floorf(c);
    lo = (int)l;
    hi = min(lo + 1, dim - 1);
    fr = c - l;
}

__global__ __launch_bounds__(1024, 8) void roialign_avg3d_kernel(
    const float* __restrict__ feats, const float* __restrict__ rois,
    float* __restrict__ out)
{
    const int r    = blockIdx.x;   // roi
    const int cb   = blockIdx.y;   // channel octet
    const int tid  = threadIdx.x;
    const int zs   = tid >> 6;     // wave = z-sample 0..15
    const int lane = tid & 63;
    const int xb   = lane & 7;     // x-bin (covers both its x-samples)
    const int ysi  = lane >> 3;    // y-sample sub-index 0..7

    __shared__ float stage[NPL * 34 * SROW];   // 70448 B
    __shared__ float bins[16 * 64];            // 4096 B

    // --- roi params (block-uniform) ---
    const float* rr = rois + r * 7;
    const int   b  = (int)rr[0];
    const float x1 = rr[1]*0.25f, y1v = rr[2]*0.25f, z1v = rr[3]*0.25f;
    const float x2 = rr[4]*0.25f, y2v = rr[5]*0.25f, z2v = rr[6]*0.25f;
    const float rw = fmaxf(x2-x1, 1.0f), rh = fmaxf(y2v-y1v, 1.0f), rd = fmaxf(z2v-z1v, 1.0f);
    const float bsx = rw*0.125f, bsy = rh*0.125f, bsz = rd*0.125f;

    // --- staged window (full roi sub-volume, all 16 z-samples) ---
    const float xc0f = x1 + 0.25f*bsx, xc15f = x1 + 7.75f*bsx;
    int x0   = (int)floorf(fminf(fmaxf(xc0f, 0.0f), 127.0f));
    int xhiR = min((int)floorf(fminf(fmaxf(xc15f, 0.0f), 127.0f)) + 1, Ww-1);
    int xext = xhiR - x0 + 1;
    if (xext < 4) xext = 4;
    if (x0 + xext > Ww) x0 = Ww - xext;

    const float yc0f = y1v + 0.25f*bsy, yc15f = y1v + 7.75f*bsy;
    const int y0   = (int)floorf(fminf(fmaxf(yc0f, 0.0f), 127.0f));
    const int yhiR = min((int)floorf(fminf(fmaxf(yc15f, 0.0f), 127.0f)) + 1, Hh-1);
    const int yext = yhiR - y0 + 1;

    const float zc0f = z1v + 0.25f*bsz, zc15f = z1v + 7.75f*bsz;
    const int p0   = (int)floorf(fminf(fmaxf(zc0f, 0.0f), 47.0f));
    const int phiR = min((int)floorf(fminf(fmaxf(zc15f, 0.0f), 47.0f)) + 1, Dd-1);
    const int pext = phiR - p0 + 1;            // <= 14

    // --- x window weights (lane-fixed) ---
    const float xcA = x1 + (float)xb*bsx + 0.25f*bsx;
    const float xcB = x1 + (float)xb*bsx + 0.75f*bsx;
    int xloA,xhiA,xloB,xhiB; float fxA,fxB; bool vxA,vxB;
    axis_interp(xcA, Ww, xloA, xhiA, fxA, vxA);
    axis_interp(xcB, Ww, xloB, xhiB, fxB, vxB);
    const int bAbs = min(xloA, x0 + xext - 4);
    const int bx   = bAbs - x0;
    float w0=0.f, w1=0.f, w2=0.f, w3=0.f;
    {
        const int iA = xloA-bAbs, hA = xhiA-bAbs, iB = xloB-bAbs, hB = xhiB-bAbs;
        const float a0 = vxA ? (1.0f-fxA) : 0.0f, a1 = vxA ? fxA : 0.0f;
        const float b0 = vxB ? (1.0f-fxB) : 0.0f, b1 = vxB ? fxB : 0.0f;
        w0 += (iA==0)?a0:0.f; w1 += (iA==1)?a0:0.f; w2 += (iA==2)?a0:0.f; w3 += (iA==3)?a0:0.f;
        w0 += (hA==0)?a1:0.f; w1 += (hA==1)?a1:0.f; w2 += (hA==2)?a1:0.f; w3 += (hA==3)?a1:0.f;
        w0 += (iB==0)?b0:0.f; w1 += (iB==1)?b0:0.f; w2 += (iB==2)?b0:0.f; w3 += (iB==3)?b0:0.f;
        w0 += (hB==0)?b1:0.f; w1 += (hB==1)?b1:0.f; w2 += (hB==2)?b1:0.f; w3 += (hB==3)?b1:0.f;
    }

    // --- z interp (per wave) ---
    const float zc = z1v + (float)(zs>>1)*bsz + ((float)(zs&1)+0.5f)*0.5f*bsz;
    int zlo,zhi; float fz; bool vz;
    axis_interp(zc, Dd, zlo, zhi, fz, vz);
    const float wz0 = 1.0f - fz, wz1 = fz;
    const int pz0 = zlo - p0, pz1 = zhi - p0;

    // --- y interp, both yy groups, precomputed (lane+wave fixed) ---
    float wrow[2][4];
    int   adr[2][4];
    #pragma unroll
    for (int yy = 0; yy < 2; ++yy) {
        const int ys = yy*8 + ysi;
        const float yc = y1v + (float)(ys>>1)*bsy + ((float)(ys&1)+0.5f)*0.5f*bsy;
        int ylo,yhi; float fy; bool vy;
        axis_interp(yc, Hh, ylo, yhi, fy, vy);
        const int ly0 = ylo - y0, ly1 = yhi - y0;
        const float s = (vy && vz) ? 1.0f : 0.0f;
        const float wy0 = 1.0f - fy, wy1 = fy;
        wrow[yy][0] = s*wz0*wy0; wrow[yy][1] = s*wz0*wy1;
        wrow[yy][2] = s*wz1*wy0; wrow[yy][3] = s*wz1*wy1;
        adr[yy][0] = (pz0*34 + ly0)*SROW + bx;
        adr[yy][1] = (pz0*34 + ly1)*SROW + bx;
        adr[yy][2] = (pz1*34 + ly0)*SROW + bx;
        adr[yy][3] = (pz1*34 + ly1)*SROW + bx;
    }

    // --- staging map (thread-fixed; init-only divisions) ---
    const int rowN = yext * xext;
    const int stage_n = pext * rowN;
    int soff[PRE], goff[PRE]; bool act[PRE];
    #pragma unroll
    for (int k = 0; k < PRE; ++k) {
        const int idx = tid + k*1024;
        const int p   = idx / rowN;
        const int rem = idx - p*rowN;
        const int yy  = rem / xext;
        const int xx  = rem - yy*xext;
        act[k]  = (idx < stage_n);
        soff[k] = (p*34 + yy)*SROW + xx;
        goff[k] = (p0 + p)*HW + (y0 + yy)*Ww + (x0 + xx);
    }

    const float* fb  = feats + (size_t)(b*C_TOT + cb*CSPLIT) * (size_t)DHW;
    const bool   bigtail = (stage_n > CAP);   // rare giant rois

    float pre[PRE];
    #pragma unroll
    for (int k = 0; k < PRE; ++k)
        pre[k] = act[k] ? fb[goff[k]] : 0.0f;
    #pragma unroll
    for (int k = 0; k < PRE; ++k)
        if (act[k]) stage[soff[k]] = pre[k];
    if (bigtail) {
        for (int idx = CAP + tid; idx < stage_n; idx += 1024) {
            const int p = idx / rowN, rem = idx - p*rowN;
            const int yy = rem / xext, xx = rem - yy*xext;
            stage[(p*34+yy)*SROW + xx] = fb[(p0+p)*HW + (y0+yy)*Ww + (x0+xx)];
        }
    }
    __syncthreads();

    for (int c = 0; c < CSPLIT; ++c) {
        // issue next channel's staging loads first (full phase of latency lead)
        if (c + 1 < CSPLIT) {
            const float* gp = fb + (size_t)(c+1)*DHW;
            #pragma unroll
            for (int k = 0; k < PRE; ++k)
                pre[k] = act[k] ? gp[goff[k]] : 0.0f;
        }
        // --- sample channel c from LDS: 2 bin-samples per lane ---
        #pragma unroll
        for (int yy = 0; yy < 2; ++yy) {
            float v = 0.0f;
            #pragma unroll
            for (int rq = 0; rq < 4; ++rq) {
                const float* sp = &stage[adr[yy][rq]];
                lf2 u0 = *(const lf2*)sp;
                lf2 u1 = *(const lf2*)(sp+2);
                v += wrow[yy][rq] * (u0.x*w0 + u0.y*w1 + u1.x*w2 + u1.y*w3);
            }
            v += __shfl_xor(v, 8);           // reduce y-sample pair
            if (!(ysi & 1)) {
                const int yb = yy*4 + (ysi>>1);
                bins[zs*64 + yb*8 + xb] = v;
            }
        }
        __syncthreads();   // bins ready; stage consumed

        // --- pool+store c (343 threads) overlapped with stage-write c+1 ---
        if (tid < 343) {
            const int w_ = tid % 7, h_ = (tid/7) % 7, dz = tid/49;
            float acc = 0.0f;
            #pragma unroll
            for (int g = 0; g < 4; ++g) {
                const float* bz = &bins[(2*dz+g)*64];
                acc += bz[h_*8+w_]       + bz[h_*8+w_+1]
                     + bz[(h_+1)*8+w_]   + bz[(h_+1)*8+w_+1];
            }
            acc *= (1.0f/64.0f);
            const int cg = cb*CSPLIT + c;
            out[(((size_t)r*C_TOT + cg)*7 + dz)*49 + h_*7 + w_] = acc;
        }
        if (c + 1 < CSPLIT) {
            #pragma unroll
            for (int k = 0; k < PRE; ++k)
                if (act[k]) stage[soff[k]] = pre[k];
            if (bigtail) {
                const float* gp = fb + (size_t)(c+1)*DHW;
                for (int idx = CAP + tid; idx < stage_n; idx += 1024) {
                    const int p = idx / rowN, rem = idx - p*rowN;
                    const int yy2 = rem / xext, xx = rem - yy2*xext;
                    stage[(p*34+yy2)*SROW + xx] = gp[(p0+p)*HW + (y0+yy2)*Ww + (x0+xx)];
                }
            }
        }
        __syncthreads();   // stage c+1 ready; bins consumed
    }
}

extern "C" void kernel_launch(void* const* d_in, const int* in_sizes, int n_in,
                              void* d_out, int out_size, void* d_ws, size_t ws_size,
                              hipStream_t stream) {
    const float* feats = (const float*)d_in[0];
    const float* rois  = (const float*)d_in[1];
    float* out = (float*)d_out;
    const int R = in_sizes[1] / 7;   // 64
    dim3 grid(R, C_TOT / CSPLIT);
    roialign_avg3d_kernel<<<grid, 1024, 0, stream>>>(feats, rois, out);
}

// Round 7
// 78.762 us; speedup vs baseline: 1.7156x; 1.7156x over previous
//
#include <hip/hip_runtime.h>

#define C_TOT 64
#define Dd 48
#define Hh 128
#define Ww 128
#define HW (Hh*Ww)
#define DHW (Dd*HW)
#define CSPLIT 8
#define SROW 37             // stage row stride (floats), odd => bank spread
#define NPL 14              // max staged z-planes
#define PRE 4               // prefetch regs/thread (covers 4096 elems)
#define CAP (PRE*1024)

typedef float lf2 __attribute__((ext_vector_type(2), aligned(4)));

__device__ __forceinline__ void axis_interp(float c, int dim, int& lo, int& hi,
                                            float& fr, bool& valid) {
    valid = (c >= -1.0f) && (c <= (float)dim);
    c = fminf(fmaxf(c, 0.0f), (float)(dim - 1));
    float l = floorf(c);
    lo = (int)l;
    hi = min(lo + 1, dim - 1);
    fr = c - l;
}

__global__ __launch_bounds__(1024, 2) void roialign_avg3d_kernel(
    const float* __restrict__ feats, const float* __restrict__ rois,
    float* __restrict__ out)
{
    const int r    = blockIdx.x;   // roi
    const int cb   = blockIdx.y;   // channel octet
    const int tid  = threadIdx.x;
    const int zs   = tid >> 6;     // wave = z-sample 0..15
    const int lane = tid & 63;
    const int xb   = lane & 7;     // x-bin (covers both its x-samples)
    const int ysi  = lane >> 3;    // y-sample sub-index 0..7

    __shared__ float stage[NPL * 34 * SROW];   // 70448 B
    __shared__ float bins[16 * 64];            // 4096 B

    // --- roi params (block-uniform) ---
    const float* rr = rois + r * 7;
    const int   b  = (int)rr[0];
    const float x1 = rr[1]*0.25f, y1v = rr[2]*0.25f, z1v = rr[3]*0.25f;
    const float x2 = rr[4]*0.25f, y2v = rr[5]*0.25f, z2v = rr[6]*0.25f;
    const float rw = fmaxf(x2-x1, 1.0f), rh = fmaxf(y2v-y1v, 1.0f), rd = fmaxf(z2v-z1v, 1.0f);
    const float bsx = rw*0.125f, bsy = rh*0.125f, bsz = rd*0.125f;

    // --- staged window (full roi sub-volume, all 16 z-samples) ---
    const float xc0f = x1 + 0.25f*bsx, xc15f = x1 + 7.75f*bsx;
    int x0   = (int)floorf(fminf(fmaxf(xc0f, 0.0f), 127.0f));
    int xhiR = min((int)floorf(fminf(fmaxf(xc15f, 0.0f), 127.0f)) + 1, Ww-1);
    int xext = xhiR - x0 + 1;
    if (xext < 4) xext = 4;
    if (x0 + xext > Ww) x0 = Ww - xext;

    const float yc0f = y1v + 0.25f*bsy, yc15f = y1v + 7.75f*bsy;
    const int y0   = (int)floorf(fminf(fmaxf(yc0f, 0.0f), 127.0f));
    const int yhiR = min((int)floorf(fminf(fmaxf(yc15f, 0.0f), 127.0f)) + 1, Hh-1);
    const int yext = yhiR - y0 + 1;

    const float zc0f = z1v + 0.25f*bsz, zc15f = z1v + 7.75f*bsz;
    const int p0   = (int)floorf(fminf(fmaxf(zc0f, 0.0f), 47.0f));
    const int phiR = min((int)floorf(fminf(fmaxf(zc15f, 0.0f), 47.0f)) + 1, Dd-1);
    const int pext = phiR - p0 + 1;            // <= 14

    // --- x window weights (lane-fixed) ---
    const float xcA = x1 + (float)xb*bsx + 0.25f*bsx;
    const float xcB = x1 + (float)xb*bsx + 0.75f*bsx;
    int xloA,xhiA,xloB,xhiB; float fxA,fxB; bool vxA,vxB;
    axis_interp(xcA, Ww, xloA, xhiA, fxA, vxA);
    axis_interp(xcB, Ww, xloB, xhiB, fxB, vxB);
    const int bAbs = min(xloA, x0 + xext - 4);
    const int bx   = bAbs - x0;
    float w0=0.f, w1=0.f, w2=0.f, w3=0.f;
    {
        const int iA = xloA-bAbs, hA = xhiA-bAbs, iB = xloB-bAbs, hB = xhiB-bAbs;
        const float a0 = vxA ? (1.0f-fxA) : 0.0f, a1 = vxA ? fxA : 0.0f;
        const float b0 = vxB ? (1.0f-fxB) : 0.0f, b1 = vxB ? fxB : 0.0f;
        w0 += (iA==0)?a0:0.f; w1 += (iA==1)?a0:0.f; w2 += (iA==2)?a0:0.f; w3 += (iA==3)?a0:0.f;
        w0 += (hA==0)?a1:0.f; w1 += (hA==1)?a1:0.f; w2 += (hA==2)?a1:0.f; w3 += (hA==3)?a1:0.f;
        w0 += (iB==0)?b0:0.f; w1 += (iB==1)?b0:0.f; w2 += (iB==2)?b0:0.f; w3 += (iB==3)?b0:0.f;
        w0 += (hB==0)?b1:0.f; w1 += (hB==1)?b1:0.f; w2 += (hB==2)?b1:0.f; w3 += (hB==3)?b1:0.f;
    }

    // --- z interp (per wave) ---
    const float zc = z1v + (float)(zs>>1)*bsz + ((float)(zs&1)+0.5f)*0.5f*bsz;
    int zlo,zhi; float fz; bool vz;
    axis_interp(zc, Dd, zlo, zhi, fz, vz);
    const float wz0 = 1.0f - fz, wz1 = fz;
    const int pz0 = zlo - p0, pz1 = zhi - p0;

    // --- y interp, both yy groups, precomputed (lane+wave fixed) ---
    float wrow[2][4];
    int   adr[2][4];
    #pragma unroll
    for (int yy = 0; yy < 2; ++yy) {
        const int ys = yy*8 + ysi;
        const float yc = y1v + (float)(ys>>1)*bsy + ((float)(ys&1)+0.5f)*0.5f*bsy;
        int ylo,yhi; float fy; bool vy;
        axis_interp(yc, Hh, ylo, yhi, fy, vy);
        const int ly0 = ylo - y0, ly1 = yhi - y0;
        const float s = (vy && vz) ? 1.0f : 0.0f;
        const float wy0 = 1.0f - fy, wy1 = fy;
        wrow[yy][0] = s*wz0*wy0; wrow[yy][1] = s*wz0*wy1;
        wrow[yy][2] = s*wz1*wy0; wrow[yy][3] = s*wz1*wy1;
        adr[yy][0] = (pz0*34 + ly0)*SROW + bx;
        adr[yy][1] = (pz0*34 + ly1)*SROW + bx;
        adr[yy][2] = (pz1*34 + ly0)*SROW + bx;
        adr[yy][3] = (pz1*34 + ly1)*SROW + bx;
    }

    // --- staging map (thread-fixed; init-only divisions) ---
    const int rowN = yext * xext;
    const int stage_n = pext * rowN;
    int soff[PRE], goff[PRE];
    #pragma unroll
    for (int k = 0; k < PRE; ++k) {
        const int idx = tid + k*1024;
        const int p   = idx / rowN;
        const int rem = idx - p*rowN;
        const int yy  = rem / xext;
        const int xx  = rem - yy*xext;
        soff[k] = (p*34 + yy)*SROW + xx;
        goff[k] = (p0 + p)*HW + (y0 + yy)*Ww + (x0 + xx);
    }

    const float* fb = feats + (size_t)(b*C_TOT + cb*CSPLIT) * (size_t)DHW;
    const bool bigtail = (stage_n > CAP);   // rare giant rois

    float pre[PRE];
    #pragma unroll
    for (int k = 0; k < PRE; ++k)
        pre[k] = (tid + k*1024 < stage_n) ? fb[goff[k]] : 0.0f;
    #pragma unroll
    for (int k = 0; k < PRE; ++k)
        if (tid + k*1024 < stage_n) stage[soff[k]] = pre[k];
    if (bigtail) {
        for (int idx = CAP + tid; idx < stage_n; idx += 1024) {
            const int p = idx / rowN, rem = idx - p*rowN;
            const int yy = rem / xext, xx = rem - yy*xext;
            stage[(p*34+yy)*SROW + xx] = fb[(p0+p)*HW + (y0+yy)*Ww + (x0+xx)];
        }
    }
    __syncthreads();

    for (int c = 0; c < CSPLIT; ++c) {
        // issue next channel's staging loads first (full phase of latency lead)
        if (c + 1 < CSPLIT) {
            const float* gp = fb + (size_t)(c+1)*DHW;
            #pragma unroll
            for (int k = 0; k < PRE; ++k)
                pre[k] = (tid + k*1024 < stage_n) ? gp[goff[k]] : 0.0f;
        }
        // --- sample channel c from LDS: 2 bin-samples per lane ---
        #pragma unroll
        for (int yy = 0; yy < 2; ++yy) {
            float v = 0.0f;
            #pragma unroll
            for (int rq = 0; rq < 4; ++rq) {
                const float* sp = &stage[adr[yy][rq]];
                lf2 u0 = *(const lf2*)sp;
                lf2 u1 = *(const lf2*)(sp+2);
                v += wrow[yy][rq] * (u0.x*w0 + u0.y*w1 + u1.x*w2 + u1.y*w3);
            }
            v += __shfl_xor(v, 8);           // reduce y-sample pair
            if (!(ysi & 1)) {
                const int yb = yy*4 + (ysi>>1);
                bins[zs*64 + yb*8 + xb] = v;
            }
        }
        __syncthreads();   // bins ready; stage consumed

        // --- pool+store c (343 threads) overlapped with stage-write c+1 ---
        if (tid < 343) {
            const int w_ = tid % 7, h_ = (tid/7) % 7, dz = tid/49;
            float acc = 0.0f;
            #pragma unroll
            for (int g = 0; g < 4; ++g) {
                const float* bz = &bins[(2*dz+g)*64];
                acc += bz[h_*8+w_]       + bz[h_*8+w_+1]
                     + bz[(h_+1)*8+w_]   + bz[(h_+1)*8+w_+1];
            }
            acc *= (1.0f/64.0f);
            const int cg = cb*CSPLIT + c;
            out[(((size_t)r*C_TOT + cg)*7 + dz)*49 + h_*7 + w_] = acc;
        }
        if (c + 1 < CSPLIT) {
            #pragma unroll
            for (int k = 0; k < PRE; ++k)
                if (tid + k*1024 < stage_n) stage[soff[k]] = pre[k];
            if (bigtail) {
                const float* gp = fb + (size_t)(c+1)*DHW;
                for (int idx = CAP + tid; idx < stage_n; idx += 1024) {
                    const int p = idx / rowN, rem = idx - p*rowN;
                    const int yy2 = rem / xext, xx = rem - yy2*xext;
                    stage[(p*34+yy2)*SROW + xx] = gp[(p0+p)*HW + (y0+yy2)*Ww + (x0+xx)];
                }
            }
        }
        __syncthreads();   // stage c+1 ready; bins consumed
    }
}

extern "C" void kernel_launch(void* const* d_in, const int* in_sizes, int n_in,
                              void* d_out, int out_size, void* d_ws, size_t ws_size,
                              hipStream_t stream) {
    const float* feats = (const float*)d_in[0];
    const float* rois  = (const float*)d_in[1];
    float* out = (float*)d_out;
    const int R = in_sizes[1] / 7;   // 64
    dim3 grid(R, C_TOT / CSPLIT);
    roialign_avg3d_kernel<<<grid, 1024, 0, stream>>>(feats, rois, out);
}

// Round 8
// 45.589 us; speedup vs baseline: 2.9640x; 1.7277x over previous
//
#include <hip/hip_runtime.h>

#define C_TOT 64
#define Dd 48
#define Hh 128
#define Ww 128
#define HW (Hh*Ww)
#define DHW (Dd*HW)
#define CSPLIT 8
#define SROW 37             // stage row stride (floats), odd => bank spread
#define NPL 14              // max staged z-planes

typedef float lf2 __attribute__((ext_vector_type(2), aligned(4)));

__device__ __forceinline__ void axis_interp(float c, int dim, int& lo, int& hi,
                                            float& fr, bool& valid) {
    valid = (c >= -1.0f) && (c <= (float)dim);
    c = fminf(fmaxf(c, 0.0f), (float)(dim - 1));
    float l = floorf(c);
    lo = (int)l;
    hi = min(lo + 1, dim - 1);
    fr = c - l;
}

// One DMA per (plane,row): LDS dest = uniform row base + lane*4 (m104 contract),
// global src = row start + lane (per-lane). No VGPR staging state.
__device__ __forceinline__ void gll_dword(const float* g, float* l) {
    __builtin_amdgcn_global_load_lds(
        (const __attribute__((address_space(1))) float*)g,
        (__attribute__((address_space(3))) float*)l, 4, 0, 0);
}

__device__ __forceinline__ void issue_stage(const float* gc, float* stg,
                                            int p0, int pext, int y0, int yext,
                                            int x0, int xext, int wave, int lane)
{
    if (lane < xext) {
        for (int p = 0; p < pext; ++p) {
            const float* gplane = gc + (size_t)(p0 + p) * HW + (size_t)y0 * Ww + x0 + lane;
            float* splane = stg + p * 34 * SROW;
            for (int yy = wave; yy < yext; yy += 16)
                gll_dword(gplane + yy * Ww, splane + yy * SROW);
        }
    }
}

__global__ __launch_bounds__(1024, 2) void roialign_avg3d_kernel(
    const float* __restrict__ feats, const float* __restrict__ rois,
    float* __restrict__ out)
{
    const int r    = blockIdx.x;   // roi
    const int cb   = blockIdx.y;   // channel octet
    const int tid  = threadIdx.x;
    const int zs   = tid >> 6;     // wave = z-sample 0..15
    const int lane = tid & 63;
    const int xb   = lane & 7;     // x-bin (covers both its x-samples)
    const int ysi  = lane >> 3;    // y-sample sub-index 0..7

    __shared__ float stage[NPL * 34 * SROW];   // 70448 B
    __shared__ float bins[16 * 64];            // 4096 B

    // --- roi params (block-uniform) ---
    const float* rr = rois + r * 7;
    const int   b  = (int)rr[0];
    const float x1 = rr[1]*0.25f, y1v = rr[2]*0.25f, z1v = rr[3]*0.25f;
    const float x2 = rr[4]*0.25f, y2v = rr[5]*0.25f, z2v = rr[6]*0.25f;
    const float rw = fmaxf(x2-x1, 1.0f), rh = fmaxf(y2v-y1v, 1.0f), rd = fmaxf(z2v-z1v, 1.0f);
    const float bsx = rw*0.125f, bsy = rh*0.125f, bsz = rd*0.125f;

    // --- staged window (full roi sub-volume, all 16 z-samples) ---
    const float xc0f = x1 + 0.25f*bsx, xc15f = x1 + 7.75f*bsx;
    int x0   = (int)floorf(fminf(fmaxf(xc0f, 0.0f), 127.0f));
    int xhiR = min((int)floorf(fminf(fmaxf(xc15f, 0.0f), 127.0f)) + 1, Ww-1);
    int xext = xhiR - x0 + 1;
    if (xext < 4) xext = 4;
    if (x0 + xext > Ww) x0 = Ww - xext;

    const float yc0f = y1v + 0.25f*bsy, yc15f = y1v + 7.75f*bsy;
    const int y0   = (int)floorf(fminf(fmaxf(yc0f, 0.0f), 127.0f));
    const int yhiR = min((int)floorf(fminf(fmaxf(yc15f, 0.0f), 127.0f)) + 1, Hh-1);
    const int yext = yhiR - y0 + 1;

    const float zc0f = z1v + 0.25f*bsz, zc15f = z1v + 7.75f*bsz;
    const int p0   = (int)floorf(fminf(fmaxf(zc0f, 0.0f), 47.0f));
    const int phiR = min((int)floorf(fminf(fmaxf(zc15f, 0.0f), 47.0f)) + 1, Dd-1);
    const int pext = phiR - p0 + 1;            // <= 14

    const float* fb = feats + (size_t)(b*C_TOT + cb*CSPLIT) * (size_t)DHW;

    // --- issue channel-0 staging DMA immediately; latency hides under the
    //     lane-geometry VALU below ---
    issue_stage(fb, stage, p0, pext, y0, yext, x0, xext, zs, lane);

    // --- x window weights (lane-fixed) ---
    const float xcA = x1 + (float)xb*bsx + 0.25f*bsx;
    const float xcB = x1 + (float)xb*bsx + 0.75f*bsx;
    int xloA,xhiA,xloB,xhiB; float fxA,fxB; bool vxA,vxB;
    axis_interp(xcA, Ww, xloA, xhiA, fxA, vxA);
    axis_interp(xcB, Ww, xloB, xhiB, fxB, vxB);
    const int bAbs = min(xloA, x0 + xext - 4);
    const int bx   = bAbs - x0;
    float w0=0.f, w1=0.f, w2=0.f, w3=0.f;
    {
        const int iA = xloA-bAbs, hA = xhiA-bAbs, iB = xloB-bAbs, hB = xhiB-bAbs;
        const float a0 = vxA ? (1.0f-fxA) : 0.0f, a1 = vxA ? fxA : 0.0f;
        const float b0 = vxB ? (1.0f-fxB) : 0.0f, b1 = vxB ? fxB : 0.0f;
        w0 += (iA==0)?a0:0.f; w1 += (iA==1)?a0:0.f; w2 += (iA==2)?a0:0.f; w3 += (iA==3)?a0:0.f;
        w0 += (hA==0)?a1:0.f; w1 += (hA==1)?a1:0.f; w2 += (hA==2)?a1:0.f; w3 += (hA==3)?a1:0.f;
        w0 += (iB==0)?b0:0.f; w1 += (iB==1)?b0:0.f; w2 += (iB==2)?b0:0.f; w3 += (iB==3)?b0:0.f;
        w0 += (hB==0)?b1:0.f; w1 += (hB==1)?b1:0.f; w2 += (hB==2)?b1:0.f; w3 += (hB==3)?b1:0.f;
    }

    // --- z interp (per wave) ---
    const float zc = z1v + (float)(zs>>1)*bsz + ((float)(zs&1)+0.5f)*0.5f*bsz;
    int zlo,zhi; float fz; bool vz;
    axis_interp(zc, Dd, zlo, zhi, fz, vz);
    const float wz0 = 1.0f - fz, wz1 = fz;
    const int pz0 = zlo - p0, pz1 = zhi - p0;

    // --- y interp, both yy groups (lane+wave fixed) ---
    float wrow[2][4];
    int   adr[2][4];
    #pragma unroll
    for (int yy = 0; yy < 2; ++yy) {
        const int ys = yy*8 + ysi;
        const float yc = y1v + (float)(ys>>1)*bsy + ((float)(ys&1)+0.5f)*0.5f*bsy;
        int ylo,yhi; float fy; bool vy;
        axis_interp(yc, Hh, ylo, yhi, fy, vy);
        const int ly0 = ylo - y0, ly1 = yhi - y0;
        const float s = (vy && vz) ? 1.0f : 0.0f;
        const float wy0 = 1.0f - fy, wy1 = fy;
        wrow[yy][0] = s*wz0*wy0; wrow[yy][1] = s*wz0*wy1;
        wrow[yy][2] = s*wz1*wy0; wrow[yy][3] = s*wz1*wy1;
        adr[yy][0] = (pz0*34 + ly0)*SROW + bx;
        adr[yy][1] = (pz0*34 + ly1)*SROW + bx;
        adr[yy][2] = (pz1*34 + ly0)*SROW + bx;
        adr[yy][3] = (pz1*34 + ly1)*SROW + bx;
    }

    asm volatile("s_waitcnt vmcnt(0)" ::: "memory");  // own DMAs landed
    __syncthreads();                                  // everyone's landed

    for (int c = 0; c < CSPLIT; ++c) {
        // --- sample channel c from LDS: 2 bin-samples per lane ---
        #pragma unroll
        for (int yy = 0; yy < 2; ++yy) {
            float v = 0.0f;
            #pragma unroll
            for (int rq = 0; rq < 4; ++rq) {
                const float* sp = &stage[adr[yy][rq]];
                lf2 u0 = *(const lf2*)sp;
                lf2 u1 = *(const lf2*)(sp+2);
                v += wrow[yy][rq] * (u0.x*w0 + u0.y*w1 + u1.x*w2 + u1.y*w3);
            }
            v += __shfl_xor(v, 8);           // reduce y-sample pair
            if (!(ysi & 1)) {
                const int yb = yy*4 + (ysi>>1);
                bins[zs*64 + yb*8 + xb] = v;
            }
        }
        __syncthreads();   // stage fully consumed; bins written

        // --- issue channel c+1 staging DMA (drains at the barrier below) ---
        if (c + 1 < CSPLIT)
            issue_stage(fb + (size_t)(c+1)*DHW, stage, p0, pext, y0, yext, x0, xext, zs, lane);

        // --- pool+store c (343 threads) overlapped with the DMA in flight ---
        if (tid < 343) {
            const int w_ = tid % 7, h_ = (tid/7) % 7, dz = tid/49;
            float acc = 0.0f;
            #pragma unroll
            for (int g = 0; g < 4; ++g) {
                const float* bz = &bins[(2*dz+g)*64];
                acc += bz[h_*8+w_]       + bz[h_*8+w_+1]
                     + bz[(h_+1)*8+w_]   + bz[(h_+1)*8+w_+1];
            }
            acc *= (1.0f/64.0f);
            const int cg = cb*CSPLIT + c;
            out[(((size_t)r*C_TOT + cg)*7 + dz)*49 + h_*7 + w_] = acc;
        }

        asm volatile("s_waitcnt vmcnt(0)" ::: "memory");  // own DMAs landed
        __syncthreads();                                  // stage c+1 ready; bins consumed
    }
}

extern "C" void kernel_launch(void* const* d_in, const int* in_sizes, int n_in,
                              void* d_out, int out_size, void* d_ws, size_t ws_size,
                              hipStream_t stream) {
    const float* feats = (const float*)d_in[0];
    const float* rois  = (const float*)d_in[1];
    float* out = (float*)d_out;
    const int R = in_sizes[1] / 7;   // 64
    dim3 grid(R, C_TOT / CSPLIT);
    roialign_avg3d_kernel<<<grid, 1024, 0, stream>>>(feats, rois, out);
}